// Round 7
// baseline (228.427 us; speedup 1.0000x reference)
//
#include <hip/hip_runtime.h>
#include <hip/hip_bf16.h>

#define NFEAT 1024
#define NHEAD 16
#define DK 64
#define TCHUNK 1024
#define MAXTOK 4096
#define NSPLIT 6

using bf16x8 = __attribute__((ext_vector_type(8))) short;
using f32x4  = __attribute__((ext_vector_type(4))) float;

__device__ __forceinline__ short f2bf(float f) {
    __hip_bfloat16 h = __float2bfloat16(f);
    return *reinterpret_cast<short*>(&h);
}

// native 2^x (v_exp_f32)
__device__ __forceinline__ float exp2fast(float x) {
    return __builtin_amdgcn_exp2f(x);
}

// log2(e)/sqrt(DK): folds both the 1/sqrt(64) and the exp->exp2 conversion
#define QSCALE 0.1803368801f

// ---------------------------------------------------------------------------
// pack: blocks [0,1024): transpose+convert W{q,k,v,o} -> Wt[4096 n][1024 k] bf16
//       blocks [1024,1152): convert x -> xb bf16
// ---------------------------------------------------------------------------
__global__ __launch_bounds__(256) void pack_kernel(
    const float* __restrict__ x,
    const float* __restrict__ Wq, const float* __restrict__ Wk,
    const float* __restrict__ Wv, const float* __restrict__ Wo,
    short* __restrict__ xb, short* __restrict__ Wt) {
    const int b = blockIdx.x;
    const int t = threadIdx.x;
    if (b < 1024) {
        __shared__ short T[64][72];
        const int w = b >> 8, tile = b & 255;
        const int k0 = (tile >> 4) << 6, n0 = (tile & 15) << 6;
        const float* W = (w == 0) ? Wq : (w == 1) ? Wk : (w == 2) ? Wv : Wo;
        const int r = t >> 2, cs = (t & 3) << 4;
        #pragma unroll
        for (int u = 0; u < 4; ++u) {
            float4 v = *reinterpret_cast<const float4*>(
                &W[(size_t)(k0 + r) * NFEAT + n0 + cs + u * 4]);
            T[cs + u * 4 + 0][r] = f2bf(v.x);
            T[cs + u * 4 + 1][r] = f2bf(v.y);
            T[cs + u * 4 + 2][r] = f2bf(v.z);
            T[cs + u * 4 + 3][r] = f2bf(v.w);
        }
        __syncthreads();
        const int c = t >> 2, rs = (t & 3) << 4;
        bf16x8 a0 = *reinterpret_cast<const bf16x8*>(&T[c][rs]);
        bf16x8 a1 = *reinterpret_cast<const bf16x8*>(&T[c][rs + 8]);
        size_t drow = (size_t)(w * 1024 + n0 + c) * NFEAT + k0 + rs;
        *reinterpret_cast<bf16x8*>(&Wt[drow]) = a0;
        *reinterpret_cast<bf16x8*>(&Wt[drow + 8]) = a1;
    } else {
        const int e0 = ((b - 1024) * 256 + t) * 32;
        #pragma unroll
        for (int u = 0; u < 4; ++u) {
            float4 v0 = *reinterpret_cast<const float4*>(&x[e0 + u * 8]);
            float4 v1 = *reinterpret_cast<const float4*>(&x[e0 + u * 8 + 4]);
            bf16x8 o;
            o[0] = f2bf(v0.x); o[1] = f2bf(v0.y); o[2] = f2bf(v0.z); o[3] = f2bf(v0.w);
            o[4] = f2bf(v1.x); o[5] = f2bf(v1.y); o[6] = f2bf(v1.z); o[7] = f2bf(v1.w);
            *reinterpret_cast<bf16x8*>(&xb[e0 + u * 8]) = o;
        }
    }
}

// ---------------------------------------------------------------------------
// QKV MFMA GEMM: qkvb[1024 t][3072] = xb @ Wqkv + bias (Q cols scaled QSCALE).
// ---------------------------------------------------------------------------
__global__ __launch_bounds__(256) void qkv_gemm(
    const short* __restrict__ xb, const short* __restrict__ Wt,
    const float* __restrict__ bq, const float* __restrict__ bk,
    const float* __restrict__ bv, short* __restrict__ qkvb) {
    __shared__ short As[64][72];
    __shared__ short Bs[128][72];
    const int tid = threadIdx.x;
    const int lane = tid & 63;
    const int w = tid >> 6;
    const int l15 = lane & 15, lg = lane >> 4;
    const int wr = w >> 1, wc = w & 1;
    const int m0 = blockIdx.y << 6, n0 = blockIdx.x << 7;
    const int sel = n0 >> 10;
    const float* bias = (sel == 0) ? bq : (sel == 1) ? bk : bv;
    const float oscale = (sel == 0) ? QSCALE : 1.0f;

    f32x4 acc[2][4];
    #pragma unroll
    for (int i = 0; i < 2; ++i)
        #pragma unroll
        for (int j = 0; j < 4; ++j) acc[i][j] = (f32x4){0.f, 0.f, 0.f, 0.f};

    for (int k0 = 0; k0 < NFEAT; k0 += 64) {
        #pragma unroll
        for (int r = 0; r < 2; ++r) {
            int f = tid + (r << 8);
            int row = f >> 3, kc = (f & 7) << 3;
            *reinterpret_cast<bf16x8*>(&As[row][kc]) =
                *reinterpret_cast<const bf16x8*>(&xb[(size_t)(m0 + row) * NFEAT + k0 + kc]);
        }
        #pragma unroll
        for (int r = 0; r < 4; ++r) {
            int f = tid + (r << 8);
            int row = f >> 3, kc = (f & 7) << 3;
            *reinterpret_cast<bf16x8*>(&Bs[row][kc]) =
                *reinterpret_cast<const bf16x8*>(&Wt[(size_t)(n0 + row) * NFEAT + k0 + kc]);
        }
        __syncthreads();
        #pragma unroll
        for (int kk = 0; kk < 2; ++kk) {
            bf16x8 am[2], bn[4];
            #pragma unroll
            for (int mi = 0; mi < 2; ++mi)
                am[mi] = *reinterpret_cast<const bf16x8*>(
                    &As[wr * 32 + mi * 16 + l15][kk * 32 + lg * 8]);
            #pragma unroll
            for (int ni = 0; ni < 4; ++ni)
                bn[ni] = *reinterpret_cast<const bf16x8*>(
                    &Bs[wc * 64 + ni * 16 + l15][kk * 32 + lg * 8]);
            #pragma unroll
            for (int mi = 0; mi < 2; ++mi)
                #pragma unroll
                for (int ni = 0; ni < 4; ++ni)
                    acc[mi][ni] = __builtin_amdgcn_mfma_f32_16x16x32_bf16(
                        am[mi], bn[ni], acc[mi][ni], 0, 0, 0);
        }
        __syncthreads();
    }
    #pragma unroll
    for (int mi = 0; mi < 2; ++mi)
        #pragma unroll
        for (int rr = 0; rr < 4; ++rr) {
            int m = m0 + wr * 32 + mi * 16 + lg * 4 + rr;
            #pragma unroll
            for (int ni = 0; ni < 4; ++ni) {
                int n = n0 + wc * 64 + ni * 16 + l15;
                float v = (acc[mi][ni][rr] + bias[n & 1023]) * oscale;
                qkvb[(size_t)m * 3072 + n] = f2bf(v);
            }
        }
}

// ---------------------------------------------------------------------------
// Output MFMA GEMM: out[1024][1024] f32 = ctxb @ Wo + bo.
// ---------------------------------------------------------------------------
__global__ __launch_bounds__(256) void out_gemm(
    const short* __restrict__ ctxb, const short* __restrict__ Wt,
    const float* __restrict__ bo, float* __restrict__ out) {
    __shared__ short As[64][72];
    __shared__ short Bs[64][72];
    const int tid = threadIdx.x;
    const int lane = tid & 63;
    const int w = tid >> 6;
    const int l15 = lane & 15, lg = lane >> 4;
    const int wr = w >> 1, wc = w & 1;
    const int m0 = blockIdx.y << 6, n0 = blockIdx.x << 6;

    f32x4 acc[2][2];
    #pragma unroll
    for (int i = 0; i < 2; ++i)
        #pragma unroll
        for (int j = 0; j < 2; ++j) acc[i][j] = (f32x4){0.f, 0.f, 0.f, 0.f};

    for (int k0 = 0; k0 < NFEAT; k0 += 64) {
        #pragma unroll
        for (int r = 0; r < 2; ++r) {
            int f = tid + (r << 8);
            int row = f >> 3, kc = (f & 7) << 3;
            *reinterpret_cast<bf16x8*>(&As[row][kc]) =
                *reinterpret_cast<const bf16x8*>(&ctxb[(size_t)(m0 + row) * NFEAT + k0 + kc]);
            *reinterpret_cast<bf16x8*>(&Bs[row][kc]) =
                *reinterpret_cast<const bf16x8*>(
                    &Wt[(size_t)(3072 + n0 + row) * NFEAT + k0 + kc]);
        }
        __syncthreads();
        #pragma unroll
        for (int kk = 0; kk < 2; ++kk) {
            bf16x8 am[2], bn[2];
            #pragma unroll
            for (int mi = 0; mi < 2; ++mi)
                am[mi] = *reinterpret_cast<const bf16x8*>(
                    &As[wr * 32 + mi * 16 + l15][kk * 32 + lg * 8]);
            #pragma unroll
            for (int ni = 0; ni < 2; ++ni)
                bn[ni] = *reinterpret_cast<const bf16x8*>(
                    &Bs[wc * 32 + ni * 16 + l15][kk * 32 + lg * 8]);
            #pragma unroll
            for (int mi = 0; mi < 2; ++mi)
                #pragma unroll
                for (int ni = 0; ni < 2; ++ni)
                    acc[mi][ni] = __builtin_amdgcn_mfma_f32_16x16x32_bf16(
                        am[mi], bn[ni], acc[mi][ni], 0, 0, 0);
        }
        __syncthreads();
    }
    #pragma unroll
    for (int mi = 0; mi < 2; ++mi)
        #pragma unroll
        for (int rr = 0; rr < 4; ++rr) {
            int m = m0 + wr * 32 + mi * 16 + lg * 4 + rr;
            #pragma unroll
            for (int ni = 0; ni < 2; ++ni) {
                int n = n0 + wc * 32 + ni * 16 + l15;
                out[(size_t)m * NFEAT + n] = acc[mi][ni][rr] + bo[n];
            }
        }
}

// ---------------------------------------------------------------------------
// gather: kg[16 h][4096 tok][64 d] bf16 and vt[16 h][64 d][4096 tok] bf16.
// ---------------------------------------------------------------------------
__global__ __launch_bounds__(256) void gather_kv(
    const float* __restrict__ kc, const float* __restrict__ vc,
    const short* __restrict__ qkvb, const int* __restrict__ btab,
    const int* __restrict__ soff, short* __restrict__ kg, short* __restrict__ vt) {
    __shared__ short TV[64][72];
    const int h = blockIdx.x;
    const int t0 = blockIdx.y << 6;
    const int offset = soff[0], total = offset + TCHUNK;
    const int t = threadIdx.x;
    const int row = t >> 2, ds = (t & 3) << 4;
    const int tok = t0 + row;
    short kv[16], vv[16];
    if (tok < offset) {
        int phys = btab[tok >> 5];
        size_t base = ((size_t)(phys * 32 + (tok & 31)) * NHEAD + h) * DK + ds;
        #pragma unroll
        for (int u = 0; u < 4; ++u) {
            float4 kf = *reinterpret_cast<const float4*>(&kc[base + u * 4]);
            float4 vf = *reinterpret_cast<const float4*>(&vc[base + u * 4]);
            kv[u * 4 + 0] = f2bf(kf.x); kv[u * 4 + 1] = f2bf(kf.y);
            kv[u * 4 + 2] = f2bf(kf.z); kv[u * 4 + 3] = f2bf(kf.w);
            vv[u * 4 + 0] = f2bf(vf.x); vv[u * 4 + 1] = f2bf(vf.y);
            vv[u * 4 + 2] = f2bf(vf.z); vv[u * 4 + 3] = f2bf(vf.w);
        }
    } else if (tok < total) {
        size_t base = (size_t)(tok - offset) * 3072 + 1024 + h * DK + ds;
        bf16x8 k0 = *reinterpret_cast<const bf16x8*>(&qkvb[base]);
        bf16x8 k1 = *reinterpret_cast<const bf16x8*>(&qkvb[base + 8]);
        bf16x8 v0 = *reinterpret_cast<const bf16x8*>(&qkvb[base + 1024]);
        bf16x8 v1 = *reinterpret_cast<const bf16x8*>(&qkvb[base + 1032]);
        #pragma unroll
        for (int e = 0; e < 8; ++e) {
            kv[e] = k0[e]; kv[8 + e] = k1[e];
            vv[e] = v0[e]; vv[8 + e] = v1[e];
        }
    } else {
        #pragma unroll
        for (int e = 0; e < 16; ++e) { kv[e] = 0; vv[e] = 0; }
    }
    {
        bf16x8 a, b;
        #pragma unroll
        for (int e = 0; e < 8; ++e) { a[e] = kv[e]; b[e] = kv[8 + e]; }
        size_t kb = ((size_t)h * MAXTOK + tok) * DK + ds;
        *reinterpret_cast<bf16x8*>(&kg[kb]) = a;
        *reinterpret_cast<bf16x8*>(&kg[kb + 8]) = b;
    }
    #pragma unroll
    for (int e = 0; e < 16; ++e) TV[ds + e][row] = vv[e];
    __syncthreads();
    {
        const int d = t >> 2, ts = (t & 3) << 4;
        bf16x8 a = *reinterpret_cast<const bf16x8*>(&TV[d][ts]);
        bf16x8 b = *reinterpret_cast<const bf16x8*>(&TV[d][ts + 8]);
        size_t vb = ((size_t)h * DK + d) * MAXTOK + t0 + ts;
        *reinterpret_cast<bf16x8*>(&vt[vb]) = a;
        *reinterpret_cast<bf16x8*>(&vt[vb + 8]) = b;
    }
}

// ---------------------------------------------------------------------------
// MFMA flash attention v6 — BARRIER-FREE. Grid (16 h, 16 qt, NSPLIT z),
// block 256 (4 waves). No LDS staging: K and V fragments are loaded per-lane
// straight from kg/vt (both already in MFMA B-frag layout); the per-head KV
// slice (1 MB bf16) stays L2-resident (head h -> XCD h%8). The only LDS is
// the per-wave P round-trip (D-layout -> A-frag) which needs no barrier.
// Waves run as fully independent streams; defer-max + exp2 + ones-MFMA
// row-sum as in v5. Partials to pacc, merged by merge_ctx.
// ---------------------------------------------------------------------------
__global__ __launch_bounds__(256, 6) void attn_mfma(
    const short* __restrict__ qkvb, const short* __restrict__ kg,
    const short* __restrict__ vt, const int* __restrict__ soff,
    float* __restrict__ pacc) {
    __shared__ short Ps[4][16][72];

    const int tid = threadIdx.x;
    const int lane = tid & 63;
    const int w = tid >> 6;
    const int l15 = lane & 15;
    const int lg = lane >> 4;
    const int h = blockIdx.x;
    const int qt = blockIdx.y;
    const int z = blockIdx.z;
    const int offset = soff[0];
    const int total = offset + TCHUNK;
    const int ntiles = (total + 63) >> 6;
    const int NT = (ntiles + NSPLIT - 1) / NSPLIT;
    const int tbase = z * NT;
    const int tend = min(tbase + NT, ntiles);

    const short* kbase = kg + (size_t)h * MAXTOK * DK;
    const short* vbase = vt + (size_t)h * DK * MAXTOK;

    // Q A-fragments (q = qt*64 + w*16 + l15, pre-scaled by QSCALE upstream)
    const size_t qrow = (size_t)(qt * 64 + w * 16 + l15) * 3072 + h * DK;
    bf16x8 aq0 = *reinterpret_cast<const bf16x8*>(&qkvb[qrow + lg * 8]);
    bf16x8 aq1 = *reinterpret_cast<const bf16x8*>(&qkvb[qrow + 32 + lg * 8]);

    bf16x8 ones;
    #pragma unroll
    for (int e = 0; e < 8; ++e) ones[e] = (short)0x3F80;   // bf16 1.0

    float m[4];
    f32x4 acc[4], acc1;
    #pragma unroll
    for (int r = 0; r < 4; ++r) m[r] = -1e30f;
    #pragma unroll
    for (int fc = 0; fc < 4; ++fc) acc[fc] = (f32x4){0.f, 0.f, 0.f, 0.f};
    acc1 = (f32x4){0.f, 0.f, 0.f, 0.f};

    for (int t = tbase; t < tend; ++t) {
        const int kt0 = t << 6;
        // ---- K fragments straight from global (L2-resident) ----
        bf16x8 kb0[4], kb1[4];
        #pragma unroll
        for (int fc = 0; fc < 4; ++fc) {
            size_t kb = (size_t)(kt0 + fc * 16 + l15) * DK + lg * 8;
            kb0[fc] = *reinterpret_cast<const bf16x8*>(&kbase[kb]);
            kb1[fc] = *reinterpret_cast<const bf16x8*>(&kbase[kb + 32]);
        }
        // ---- QK^T ----
        f32x4 s[4];
        __builtin_amdgcn_s_setprio(1);
        #pragma unroll
        for (int fc = 0; fc < 4; ++fc) {
            s[fc] = __builtin_amdgcn_mfma_f32_16x16x32_bf16(
                aq0, kb0[fc], (f32x4){0.f, 0.f, 0.f, 0.f}, 0, 0, 0);
            s[fc] = __builtin_amdgcn_mfma_f32_16x16x32_bf16(
                aq1, kb1[fc], s[fc], 0, 0, 0);
        }
        __builtin_amdgcn_s_setprio(0);
        if (kt0 + 64 > total) {   // uniform branch; only possible last tile
            #pragma unroll
            for (int fc = 0; fc < 4; ++fc) {
                bool valid = (kt0 + fc * 16 + l15) < total;
                #pragma unroll
                for (int r = 0; r < 4; ++r)
                    s[fc][r] = valid ? s[fc][r] : -1e30f;
            }
        }
        // ---- defer-max online softmax ----
        float lm[4];
        #pragma unroll
        for (int r = 0; r < 4; ++r)
            lm[r] = fmaxf(fmaxf(s[0][r], s[1][r]), fmaxf(s[2][r], s[3][r]));
        bool ok = lm[0] <= m[0] + 8.f && lm[1] <= m[1] + 8.f &&
                  lm[2] <= m[2] + 8.f && lm[3] <= m[3] + 8.f;
        if (!__all(ok)) {
            #pragma unroll
            for (int r = 0; r < 4; ++r) {
                float tm = lm[r];
                tm = fmaxf(tm, __shfl_xor(tm, 1));
                tm = fmaxf(tm, __shfl_xor(tm, 2));
                tm = fmaxf(tm, __shfl_xor(tm, 4));
                tm = fmaxf(tm, __shfl_xor(tm, 8));
                float mn = fmaxf(m[r], tm);
                float sc = exp2fast(m[r] - mn);
                m[r] = mn;
                acc1[r] *= sc;
                #pragma unroll
                for (int fc = 0; fc < 4; ++fc) acc[fc][r] *= sc;
            }
        }
        // ---- P = exp2(s - m) -> per-wave LDS (D layout -> A-frag layout) ----
        #pragma unroll
        for (int fc = 0; fc < 4; ++fc)
            #pragma unroll
            for (int r = 0; r < 4; ++r)
                Ps[w][lg * 4 + r][l15 + 16 * fc] = f2bf(exp2fast(s[fc][r] - m[r]));
        // ---- PV (+ row-sum via ones-MFMA), V frags straight from global ----
        #pragma unroll
        for (int ks = 0; ks < 2; ++ks) {
            bf16x8 pa = *reinterpret_cast<const bf16x8*>(
                &Ps[w][l15][ks * 32 + lg * 8]);
            __builtin_amdgcn_s_setprio(1);
            acc1 = __builtin_amdgcn_mfma_f32_16x16x32_bf16(pa, ones, acc1, 0, 0, 0);
            #pragma unroll
            for (int fc = 0; fc < 4; ++fc) {
                bf16x8 bv = *reinterpret_cast<const bf16x8*>(
                    &vbase[(size_t)(fc * 16 + l15) * MAXTOK + kt0 + ks * 32 + lg * 8]);
                acc[fc] = __builtin_amdgcn_mfma_f32_16x16x32_bf16(pa, bv, acc[fc], 0, 0, 0);
            }
            __builtin_amdgcn_s_setprio(0);
        }
    }

    // ---- write this split's partial (unnormalized) ----
    const size_t pbase = (((size_t)z * NHEAD + h) * 16 + qt) * 4224;
    #pragma unroll
    for (int r = 0; r < 4; ++r) {
        int q = w * 16 + lg * 4 + r;
        if (l15 == 0) {
            pacc[pbase + 4096 + q] = m[r];
            pacc[pbase + 4160 + q] = acc1[r];
        }
        #pragma unroll
        for (int fc = 0; fc < 4; ++fc)
            pacc[pbase + q * 64 + l15 + 16 * fc] = acc[fc][r];
    }
}

// ---------------------------------------------------------------------------
// merge NSPLIT split partials -> ctxb bf16 [1024 t][1024 (h*64+d)]
// ---------------------------------------------------------------------------
__global__ __launch_bounds__(256) void merge_ctx(
    const float* __restrict__ pacc, short* __restrict__ ctxb) {
    const int h = blockIdx.x, qt = blockIdx.y;
    const int t = threadIdx.x;
    const int q = t >> 2, ds = (t & 3) << 4;
    size_t b[NSPLIT];
    float mz[NSPLIT], lz[NSPLIT];
    float M = -1e30f;
    #pragma unroll
    for (int z = 0; z < NSPLIT; ++z) {
        b[z] = (((size_t)z * NHEAD + h) * 16 + qt) * 4224;
        mz[z] = pacc[b[z] + 4096 + q];
        lz[z] = pacc[b[z] + 4160 + q];
        M = fmaxf(M, mz[z]);
    }
    float L = 0.f, ez[NSPLIT];
    #pragma unroll
    for (int z = 0; z < NSPLIT; ++z) {
        ez[z] = __builtin_amdgcn_exp2f(mz[z] - M);
        L += lz[z] * ez[z];
    }
    float inv = 1.f / L;
    bf16x8 o0, o1;
    #pragma unroll
    for (int j = 0; j < 8; ++j) {
        float v = 0.f;
        #pragma unroll
        for (int z = 0; z < NSPLIT; ++z)
            v += pacc[b[z] + q * 64 + ds + j] * ez[z];
        o0[j] = f2bf(v * inv);
    }
    #pragma unroll
    for (int j = 0; j < 8; ++j) {
        float v = 0.f;
        #pragma unroll
        for (int z = 0; z < NSPLIT; ++z)
            v += pacc[b[z] + q * 64 + ds + 8 + j] * ez[z];
        o1[j] = f2bf(v * inv);
    }
    size_t ob = (size_t)(qt * 64 + q) * NFEAT + h * DK + ds;
    *reinterpret_cast<bf16x8*>(&ctxb[ob]) = o0;
    *reinterpret_cast<bf16x8*>(&ctxb[ob + 8]) = o1;
}

extern "C" void kernel_launch(void* const* d_in, const int* in_sizes, int n_in,
                              void* d_out, int out_size, void* d_ws, size_t ws_size,
                              hipStream_t stream) {
    const float* x   = (const float*)d_in[0];
    const float* Wq  = (const float*)d_in[1];
    const float* bq  = (const float*)d_in[2];
    const float* Wk  = (const float*)d_in[3];
    const float* bk  = (const float*)d_in[4];
    const float* Wv  = (const float*)d_in[5];
    const float* bv  = (const float*)d_in[6];
    const float* Wo  = (const float*)d_in[7];
    const float* bo  = (const float*)d_in[8];
    const float* kc  = (const float*)d_in[9];
    const float* vc  = (const float*)d_in[10];
    const int*   bt  = (const int*)d_in[11];
    const int*   so  = (const int*)d_in[12];

    short* xb   = (short*)d_ws;                       // 1M bf16
    short* Wt   = xb + (size_t)1024 * 1024;           // 4M bf16
    short* qkvb = Wt + (size_t)4096 * 1024;           // 3M bf16
    short* kg   = qkvb + (size_t)1024 * 3072;         // 4M bf16
    short* vtb  = kg + (size_t)NHEAD * MAXTOK * DK;   // 4M bf16
    float* pacc = (float*)(vtb + (size_t)NHEAD * DK * MAXTOK);  // NSPLIT*256*4224 f32
    short* ctxb = (short*)(pacc + (size_t)NSPLIT * 256 * 4224); // 1M bf16

    pack_kernel<<<dim3(1152), 256, 0, stream>>>(x, Wq, Wk, Wv, Wo, xb, Wt);
    qkv_gemm<<<dim3(24, 16), 256, 0, stream>>>(xb, Wt, bq, bk, bv, qkvb);
    gather_kv<<<dim3(16, 64), 256, 0, stream>>>(kc, vc, qkvb, bt, so, kg, vtb);
    attn_mfma<<<dim3(16, 16, NSPLIT), 256, 0, stream>>>(qkvb, kg, vtb, so, pacc);
    merge_ctx<<<dim3(16, 16), 256, 0, stream>>>(pacc, ctxb);
    out_gemm<<<dim3(16, 16), 256, 0, stream>>>(ctxb, Wt, bo, (float*)d_out);
}

// Round 8
// 112.526 us; speedup vs baseline: 2.0300x; 2.0300x over previous
//
#include <hip/hip_runtime.h>
#include <hip/hip_bf16.h>

#define NFEAT 1024
#define NHEAD 16
#define DK 64
#define TCHUNK 1024
#define MAXTOK 4096
#define NSPLIT 4

using bf16x8 = __attribute__((ext_vector_type(8))) short;
using f32x4  = __attribute__((ext_vector_type(4))) float;

__device__ __forceinline__ short f2bf(float f) {
    __hip_bfloat16 h = __float2bfloat16(f);
    return *reinterpret_cast<short*>(&h);
}

// native 2^x (v_exp_f32)
__device__ __forceinline__ float exp2fast(float x) {
    return __builtin_amdgcn_exp2f(x);
}

// log2(e)/sqrt(DK): folds both the 1/sqrt(64) and the exp->exp2 conversion
#define QSCALE 0.1803368801f

// ---------------------------------------------------------------------------
// pack: blocks [0,1024): transpose+convert W{q,k,v,o} -> Wt[4096 n][1024 k] bf16
//       blocks [1024,1152): convert x -> xb bf16
// ---------------------------------------------------------------------------
__global__ __launch_bounds__(256) void pack_kernel(
    const float* __restrict__ x,
    const float* __restrict__ Wq, const float* __restrict__ Wk,
    const float* __restrict__ Wv, const float* __restrict__ Wo,
    short* __restrict__ xb, short* __restrict__ Wt) {
    const int b = blockIdx.x;
    const int t = threadIdx.x;
    if (b < 1024) {
        __shared__ short T[64][72];
        const int w = b >> 8, tile = b & 255;
        const int k0 = (tile >> 4) << 6, n0 = (tile & 15) << 6;
        const float* W = (w == 0) ? Wq : (w == 1) ? Wk : (w == 2) ? Wv : Wo;
        const int r = t >> 2, cs = (t & 3) << 4;
        #pragma unroll
        for (int u = 0; u < 4; ++u) {
            float4 v = *reinterpret_cast<const float4*>(
                &W[(size_t)(k0 + r) * NFEAT + n0 + cs + u * 4]);
            T[cs + u * 4 + 0][r] = f2bf(v.x);
            T[cs + u * 4 + 1][r] = f2bf(v.y);
            T[cs + u * 4 + 2][r] = f2bf(v.z);
            T[cs + u * 4 + 3][r] = f2bf(v.w);
        }
        __syncthreads();
        const int c = t >> 2, rs = (t & 3) << 4;
        bf16x8 a0 = *reinterpret_cast<const bf16x8*>(&T[c][rs]);
        bf16x8 a1 = *reinterpret_cast<const bf16x8*>(&T[c][rs + 8]);
        size_t drow = (size_t)(w * 1024 + n0 + c) * NFEAT + k0 + rs;
        *reinterpret_cast<bf16x8*>(&Wt[drow]) = a0;
        *reinterpret_cast<bf16x8*>(&Wt[drow + 8]) = a1;
    } else {
        const int e0 = ((b - 1024) * 256 + t) * 32;
        #pragma unroll
        for (int u = 0; u < 4; ++u) {
            float4 v0 = *reinterpret_cast<const float4*>(&x[e0 + u * 8]);
            float4 v1 = *reinterpret_cast<const float4*>(&x[e0 + u * 8 + 4]);
            bf16x8 o;
            o[0] = f2bf(v0.x); o[1] = f2bf(v0.y); o[2] = f2bf(v0.z); o[3] = f2bf(v0.w);
            o[4] = f2bf(v1.x); o[5] = f2bf(v1.y); o[6] = f2bf(v1.z); o[7] = f2bf(v1.w);
            *reinterpret_cast<bf16x8*>(&xb[e0 + u * 8]) = o;
        }
    }
}

// ---------------------------------------------------------------------------
// QKV MFMA GEMM: qkvb[1024 t][3072] = xb @ Wqkv + bias (Q cols scaled QSCALE).
// ---------------------------------------------------------------------------
__global__ __launch_bounds__(256) void qkv_gemm(
    const short* __restrict__ xb, const short* __restrict__ Wt,
    const float* __restrict__ bq, const float* __restrict__ bk,
    const float* __restrict__ bv, short* __restrict__ qkvb) {
    __shared__ short As[64][72];
    __shared__ short Bs[128][72];
    const int tid = threadIdx.x;
    const int lane = tid & 63;
    const int w = tid >> 6;
    const int l15 = lane & 15, lg = lane >> 4;
    const int wr = w >> 1, wc = w & 1;
    const int m0 = blockIdx.y << 6, n0 = blockIdx.x << 7;
    const int sel = n0 >> 10;
    const float* bias = (sel == 0) ? bq : (sel == 1) ? bk : bv;
    const float oscale = (sel == 0) ? QSCALE : 1.0f;

    f32x4 acc[2][4];
    #pragma unroll
    for (int i = 0; i < 2; ++i)
        #pragma unroll
        for (int j = 0; j < 4; ++j) acc[i][j] = (f32x4){0.f, 0.f, 0.f, 0.f};

    for (int k0 = 0; k0 < NFEAT; k0 += 64) {
        #pragma unroll
        for (int r = 0; r < 2; ++r) {
            int f = tid + (r << 8);
            int row = f >> 3, kc = (f & 7) << 3;
            *reinterpret_cast<bf16x8*>(&As[row][kc]) =
                *reinterpret_cast<const bf16x8*>(&xb[(size_t)(m0 + row) * NFEAT + k0 + kc]);
        }
        #pragma unroll
        for (int r = 0; r < 4; ++r) {
            int f = tid + (r << 8);
            int row = f >> 3, kc = (f & 7) << 3;
            *reinterpret_cast<bf16x8*>(&Bs[row][kc]) =
                *reinterpret_cast<const bf16x8*>(&Wt[(size_t)(n0 + row) * NFEAT + k0 + kc]);
        }
        __syncthreads();
        #pragma unroll
        for (int kk = 0; kk < 2; ++kk) {
            bf16x8 am[2], bn[4];
            #pragma unroll
            for (int mi = 0; mi < 2; ++mi)
                am[mi] = *reinterpret_cast<const bf16x8*>(
                    &As[wr * 32 + mi * 16 + l15][kk * 32 + lg * 8]);
            #pragma unroll
            for (int ni = 0; ni < 4; ++ni)
                bn[ni] = *reinterpret_cast<const bf16x8*>(
                    &Bs[wc * 64 + ni * 16 + l15][kk * 32 + lg * 8]);
            #pragma unroll
            for (int mi = 0; mi < 2; ++mi)
                #pragma unroll
                for (int ni = 0; ni < 4; ++ni)
                    acc[mi][ni] = __builtin_amdgcn_mfma_f32_16x16x32_bf16(
                        am[mi], bn[ni], acc[mi][ni], 0, 0, 0);
        }
        __syncthreads();
    }
    #pragma unroll
    for (int mi = 0; mi < 2; ++mi)
        #pragma unroll
        for (int rr = 0; rr < 4; ++rr) {
            int m = m0 + wr * 32 + mi * 16 + lg * 4 + rr;
            #pragma unroll
            for (int ni = 0; ni < 4; ++ni) {
                int n = n0 + wc * 64 + ni * 16 + l15;
                float v = (acc[mi][ni][rr] + bias[n & 1023]) * oscale;
                qkvb[(size_t)m * 3072 + n] = f2bf(v);
            }
        }
}

// ---------------------------------------------------------------------------
// Output MFMA GEMM: out[1024][1024] f32 = ctxb @ Wo + bo.
// ---------------------------------------------------------------------------
__global__ __launch_bounds__(256) void out_gemm(
    const short* __restrict__ ctxb, const short* __restrict__ Wt,
    const float* __restrict__ bo, float* __restrict__ out) {
    __shared__ short As[64][72];
    __shared__ short Bs[64][72];
    const int tid = threadIdx.x;
    const int lane = tid & 63;
    const int w = tid >> 6;
    const int l15 = lane & 15, lg = lane >> 4;
    const int wr = w >> 1, wc = w & 1;
    const int m0 = blockIdx.y << 6, n0 = blockIdx.x << 6;

    f32x4 acc[2][2];
    #pragma unroll
    for (int i = 0; i < 2; ++i)
        #pragma unroll
        for (int j = 0; j < 2; ++j) acc[i][j] = (f32x4){0.f, 0.f, 0.f, 0.f};

    for (int k0 = 0; k0 < NFEAT; k0 += 64) {
        #pragma unroll
        for (int r = 0; r < 2; ++r) {
            int f = tid + (r << 8);
            int row = f >> 3, kc = (f & 7) << 3;
            *reinterpret_cast<bf16x8*>(&As[row][kc]) =
                *reinterpret_cast<const bf16x8*>(&ctxb[(size_t)(m0 + row) * NFEAT + k0 + kc]);
            *reinterpret_cast<bf16x8*>(&Bs[row][kc]) =
                *reinterpret_cast<const bf16x8*>(
                    &Wt[(size_t)(3072 + n0 + row) * NFEAT + k0 + kc]);
        }
        __syncthreads();
        #pragma unroll
        for (int kk = 0; kk < 2; ++kk) {
            bf16x8 am[2], bn[2];
            #pragma unroll
            for (int mi = 0; mi < 2; ++mi)
                am[mi] = *reinterpret_cast<const bf16x8*>(
                    &As[wr * 32 + mi * 16 + l15][kk * 32 + lg * 8]);
            #pragma unroll
            for (int ni = 0; ni < 2; ++ni)
                bn[ni] = *reinterpret_cast<const bf16x8*>(
                    &Bs[wc * 32 + ni * 16 + l15][kk * 32 + lg * 8]);
            #pragma unroll
            for (int mi = 0; mi < 2; ++mi)
                #pragma unroll
                for (int ni = 0; ni < 2; ++ni)
                    acc[mi][ni] = __builtin_amdgcn_mfma_f32_16x16x32_bf16(
                        am[mi], bn[ni], acc[mi][ni], 0, 0, 0);
        }
        __syncthreads();
    }
    #pragma unroll
    for (int mi = 0; mi < 2; ++mi)
        #pragma unroll
        for (int rr = 0; rr < 4; ++rr) {
            int m = m0 + wr * 32 + mi * 16 + lg * 4 + rr;
            #pragma unroll
            for (int ni = 0; ni < 2; ++ni) {
                int n = n0 + wc * 32 + ni * 16 + l15;
                out[(size_t)m * NFEAT + n] = acc[mi][ni][rr] + bo[n];
            }
        }
}

// ---------------------------------------------------------------------------
// gather: kg[16 h][4096 tok][64 d] bf16 and vt[16 h][64 d][4096 tok] bf16.
// ---------------------------------------------------------------------------
__global__ __launch_bounds__(256) void gather_kv(
    const float* __restrict__ kc, const float* __restrict__ vc,
    const short* __restrict__ qkvb, const int* __restrict__ btab,
    const int* __restrict__ soff, short* __restrict__ kg, short* __restrict__ vt) {
    __shared__ short TV[64][72];
    const int h = blockIdx.x;
    const int t0 = blockIdx.y << 6;
    const int offset = soff[0], total = offset + TCHUNK;
    const int t = threadIdx.x;
    const int row = t >> 2, ds = (t & 3) << 4;
    const int tok = t0 + row;
    short kv[16], vv[16];
    if (tok < offset) {
        int phys = btab[tok >> 5];
        size_t base = ((size_t)(phys * 32 + (tok & 31)) * NHEAD + h) * DK + ds;
        #pragma unroll
        for (int u = 0; u < 4; ++u) {
            float4 kf = *reinterpret_cast<const float4*>(&kc[base + u * 4]);
            float4 vf = *reinterpret_cast<const float4*>(&vc[base + u * 4]);
            kv[u * 4 + 0] = f2bf(kf.x); kv[u * 4 + 1] = f2bf(kf.y);
            kv[u * 4 + 2] = f2bf(kf.z); kv[u * 4 + 3] = f2bf(kf.w);
            vv[u * 4 + 0] = f2bf(vf.x); vv[u * 4 + 1] = f2bf(vf.y);
            vv[u * 4 + 2] = f2bf(vf.z); vv[u * 4 + 3] = f2bf(vf.w);
        }
    } else if (tok < total) {
        size_t base = (size_t)(tok - offset) * 3072 + 1024 + h * DK + ds;
        bf16x8 k0 = *reinterpret_cast<const bf16x8*>(&qkvb[base]);
        bf16x8 k1 = *reinterpret_cast<const bf16x8*>(&qkvb[base + 8]);
        bf16x8 v0 = *reinterpret_cast<const bf16x8*>(&qkvb[base + 1024]);
        bf16x8 v1 = *reinterpret_cast<const bf16x8*>(&qkvb[base + 1032]);
        #pragma unroll
        for (int e = 0; e < 8; ++e) {
            kv[e] = k0[e]; kv[8 + e] = k1[e];
            vv[e] = v0[e]; vv[8 + e] = v1[e];
        }
    } else {
        #pragma unroll
        for (int e = 0; e < 16; ++e) { kv[e] = 0; vv[e] = 0; }
    }
    {
        bf16x8 a, b;
        #pragma unroll
        for (int e = 0; e < 8; ++e) { a[e] = kv[e]; b[e] = kv[8 + e]; }
        size_t kb = ((size_t)h * MAXTOK + tok) * DK + ds;
        *reinterpret_cast<bf16x8*>(&kg[kb]) = a;
        *reinterpret_cast<bf16x8*>(&kg[kb + 8]) = b;
    }
    #pragma unroll
    for (int e = 0; e < 16; ++e) TV[ds + e][row] = vv[e];
    __syncthreads();
    {
        const int d = t >> 2, ts = (t & 3) << 4;
        bf16x8 a = *reinterpret_cast<const bf16x8*>(&TV[d][ts]);
        bf16x8 b = *reinterpret_cast<const bf16x8*>(&TV[d][ts + 8]);
        size_t vb = ((size_t)h * DK + d) * MAXTOK + t0 + ts;
        *reinterpret_cast<bf16x8*>(&vt[vb]) = a;
        *reinterpret_cast<bf16x8*>(&vt[vb + 8]) = b;
    }
}

// ---------------------------------------------------------------------------
// MFMA flash attention v8 — double-buffered LDS, ONE barrier per tile.
// Grid (16 h, 16 qt, NSPLIT z), block 256 (4 waves). Iter t: issue global
// loads for tile t+1 (top), compute tile t from buf[cur] (middle), ds_write
// the t+1 regs into buf[cur^1] (bottom, vmcnt drains under compute), one
// __syncthreads. buf[cur^1]'s readers finished at the previous barrier.
// Defer-max softmax, ones-MFMA row-sum, exp2 domain as before.
// ---------------------------------------------------------------------------
__global__ __launch_bounds__(256, 3) void attn_mfma(
    const short* __restrict__ qkvb, const short* __restrict__ kg,
    const short* __restrict__ vt, const int* __restrict__ soff,
    float* __restrict__ pacc) {
    __shared__ short Ks[2][64][72];
    __shared__ short Vs[2][64][72];   // [d][tok]
    __shared__ short Ps[4][16][72];

    const int tid = threadIdx.x;
    const int lane = tid & 63;
    const int w = tid >> 6;
    const int l15 = lane & 15;
    const int lg = lane >> 4;
    const int h = blockIdx.x;
    const int qt = blockIdx.y;
    const int z = blockIdx.z;
    const int offset = soff[0];
    const int total = offset + TCHUNK;
    const int ntiles = (total + 63) >> 6;
    const int NT = (ntiles + NSPLIT - 1) / NSPLIT;
    const int tbase = z * NT;
    const int tend = min(tbase + NT, ntiles);

    const int srow = tid >> 2;            // staging row (tok for K, d for V)
    const int sds = (tid & 3) << 4;       // staging 16-elem segment

    const short* kbase = kg + (size_t)h * MAXTOK * DK;
    const short* vbase = vt + (size_t)h * DK * MAXTOK;

    // Q A-fragments (q = qt*64 + w*16 + l15, pre-scaled by QSCALE upstream)
    const size_t qrow = (size_t)(qt * 64 + w * 16 + l15) * 3072 + h * DK;
    bf16x8 aq0 = *reinterpret_cast<const bf16x8*>(&qkvb[qrow + lg * 8]);
    bf16x8 aq1 = *reinterpret_cast<const bf16x8*>(&qkvb[qrow + 32 + lg * 8]);

    bf16x8 ones;
    #pragma unroll
    for (int e = 0; e < 8; ++e) ones[e] = (short)0x3F80;   // bf16 1.0

    float m[4];
    f32x4 acc[4], acc1;
    #pragma unroll
    for (int r = 0; r < 4; ++r) m[r] = -1e30f;
    #pragma unroll
    for (int fc = 0; fc < 4; ++fc) acc[fc] = (f32x4){0.f, 0.f, 0.f, 0.f};
    acc1 = (f32x4){0.f, 0.f, 0.f, 0.f};

    bf16x8 kr0, kr1, vr0, vr1;
    if (tbase < tend) {
        // prologue: load + stage tile tbase into buf 0
        int tok0 = tbase << 6;
        size_t kb = (size_t)(tok0 + srow) * DK + sds;
        kr0 = *reinterpret_cast<const bf16x8*>(&kbase[kb]);
        kr1 = *reinterpret_cast<const bf16x8*>(&kbase[kb + 8]);
        size_t vb = (size_t)srow * MAXTOK + tok0 + sds;
        vr0 = *reinterpret_cast<const bf16x8*>(&vbase[vb]);
        vr1 = *reinterpret_cast<const bf16x8*>(&vbase[vb + 8]);
        *reinterpret_cast<bf16x8*>(&Ks[0][srow][sds]) = kr0;
        *reinterpret_cast<bf16x8*>(&Ks[0][srow][sds + 8]) = kr1;
        *reinterpret_cast<bf16x8*>(&Vs[0][srow][sds]) = vr0;
        *reinterpret_cast<bf16x8*>(&Vs[0][srow][sds + 8]) = vr1;
        __syncthreads();
    }

    int cur = 0;
    for (int t = tbase; t < tend; ++t) {
        const bool more = (t + 1 < tend);
        if (more) {   // issue next-tile loads; they drain under this compute
            int tok0 = (t + 1) << 6;
            size_t kb = (size_t)(tok0 + srow) * DK + sds;
            kr0 = *reinterpret_cast<const bf16x8*>(&kbase[kb]);
            kr1 = *reinterpret_cast<const bf16x8*>(&kbase[kb + 8]);
            size_t vb = (size_t)srow * MAXTOK + tok0 + sds;
            vr0 = *reinterpret_cast<const bf16x8*>(&vbase[vb]);
            vr1 = *reinterpret_cast<const bf16x8*>(&vbase[vb + 8]);
        }

        const int kt0 = t << 6;
        // ---- QK^T ----
        bf16x8 kb0[4], kb1[4];
        #pragma unroll
        for (int fc = 0; fc < 4; ++fc) {
            kb0[fc] = *reinterpret_cast<const bf16x8*>(&Ks[cur][fc * 16 + l15][lg * 8]);
            kb1[fc] = *reinterpret_cast<const bf16x8*>(&Ks[cur][fc * 16 + l15][32 + lg * 8]);
        }
        f32x4 s[4];
        __builtin_amdgcn_s_setprio(1);
        #pragma unroll
        for (int fc = 0; fc < 4; ++fc) {
            s[fc] = __builtin_amdgcn_mfma_f32_16x16x32_bf16(
                aq0, kb0[fc], (f32x4){0.f, 0.f, 0.f, 0.f}, 0, 0, 0);
            s[fc] = __builtin_amdgcn_mfma_f32_16x16x32_bf16(
                aq1, kb1[fc], s[fc], 0, 0, 0);
        }
        __builtin_amdgcn_s_setprio(0);
        if (kt0 + 64 > total) {   // uniform branch; only possible last tile
            #pragma unroll
            for (int fc = 0; fc < 4; ++fc) {
                bool valid = (kt0 + fc * 16 + l15) < total;
                #pragma unroll
                for (int r = 0; r < 4; ++r)
                    s[fc][r] = valid ? s[fc][r] : -1e30f;
            }
        }
        // ---- defer-max online softmax ----
        float lm[4];
        #pragma unroll
        for (int r = 0; r < 4; ++r)
            lm[r] = fmaxf(fmaxf(s[0][r], s[1][r]), fmaxf(s[2][r], s[3][r]));
        bool ok = lm[0] <= m[0] + 8.f && lm[1] <= m[1] + 8.f &&
                  lm[2] <= m[2] + 8.f && lm[3] <= m[3] + 8.f;
        if (!__all(ok)) {
            #pragma unroll
            for (int r = 0; r < 4; ++r) {
                float tm = lm[r];
                tm = fmaxf(tm, __shfl_xor(tm, 1));
                tm = fmaxf(tm, __shfl_xor(tm, 2));
                tm = fmaxf(tm, __shfl_xor(tm, 4));
                tm = fmaxf(tm, __shfl_xor(tm, 8));
                float mn = fmaxf(m[r], tm);
                float sc = exp2fast(m[r] - mn);
                m[r] = mn;
                acc1[r] *= sc;
                #pragma unroll
                for (int fc = 0; fc < 4; ++fc) acc[fc][r] *= sc;
            }
        }
        // ---- P = exp2(s - m) -> per-wave LDS (D layout -> A-frag layout) ----
        #pragma unroll
        for (int fc = 0; fc < 4; ++fc)
            #pragma unroll
            for (int r = 0; r < 4; ++r)
                Ps[w][lg * 4 + r][l15 + 16 * fc] = f2bf(exp2fast(s[fc][r] - m[r]));
        // ---- PV (+ row-sum via ones-MFMA) ----
        #pragma unroll
        for (int ks = 0; ks < 2; ++ks) {
            bf16x8 pa = *reinterpret_cast<const bf16x8*>(
                &Ps[w][l15][ks * 32 + lg * 8]);
            __builtin_amdgcn_s_setprio(1);
            acc1 = __builtin_amdgcn_mfma_f32_16x16x32_bf16(pa, ones, acc1, 0, 0, 0);
            #pragma unroll
            for (int fc = 0; fc < 4; ++fc) {
                bf16x8 bv = *reinterpret_cast<const bf16x8*>(
                    &Vs[cur][fc * 16 + l15][ks * 32 + lg * 8]);
                acc[fc] = __builtin_amdgcn_mfma_f32_16x16x32_bf16(pa, bv, acc[fc], 0, 0, 0);
            }
            __builtin_amdgcn_s_setprio(0);
        }
        // ---- stage tile t+1 into the other buffer, single barrier ----
        if (more) {
            *reinterpret_cast<bf16x8*>(&Ks[cur ^ 1][srow][sds]) = kr0;
            *reinterpret_cast<bf16x8*>(&Ks[cur ^ 1][srow][sds + 8]) = kr1;
            *reinterpret_cast<bf16x8*>(&Vs[cur ^ 1][srow][sds]) = vr0;
            *reinterpret_cast<bf16x8*>(&Vs[cur ^ 1][srow][sds + 8]) = vr1;
            __syncthreads();
            cur ^= 1;
        }
    }

    // ---- write this split's partial (unnormalized) ----
    const size_t pbase = (((size_t)z * NHEAD + h) * 16 + qt) * 4224;
    #pragma unroll
    for (int r = 0; r < 4; ++r) {
        int q = w * 16 + lg * 4 + r;
        if (l15 == 0) {
            pacc[pbase + 4096 + q] = m[r];
            pacc[pbase + 4160 + q] = acc1[r];
        }
        #pragma unroll
        for (int fc = 0; fc < 4; ++fc)
            pacc[pbase + q * 64 + l15 + 16 * fc] = acc[fc][r];
    }
}

// ---------------------------------------------------------------------------
// merge NSPLIT split partials -> ctxb bf16 [1024 t][1024 (h*64+d)]
// ---------------------------------------------------------------------------
__global__ __launch_bounds__(256) void merge_ctx(
    const float* __restrict__ pacc, short* __restrict__ ctxb) {
    const int h = blockIdx.x, qt = blockIdx.y;
    const int t = threadIdx.x;
    const int q = t >> 2, ds = (t & 3) << 4;
    size_t b[NSPLIT];
    float mz[NSPLIT], lz[NSPLIT];
    float M = -1e30f;
    #pragma unroll
    for (int z = 0; z < NSPLIT; ++z) {
        b[z] = (((size_t)z * NHEAD + h) * 16 + qt) * 4224;
        mz[z] = pacc[b[z] + 4096 + q];
        lz[z] = pacc[b[z] + 4160 + q];
        M = fmaxf(M, mz[z]);
    }
    float L = 0.f, ez[NSPLIT];
    #pragma unroll
    for (int z = 0; z < NSPLIT; ++z) {
        ez[z] = __builtin_amdgcn_exp2f(mz[z] - M);
        L += lz[z] * ez[z];
    }
    float inv = 1.f / L;
    bf16x8 o0, o1;
    #pragma unroll
    for (int j = 0; j < 8; ++j) {
        float v = 0.f;
        #pragma unroll
        for (int z = 0; z < NSPLIT; ++z)
            v += pacc[b[z] + q * 64 + ds + j] * ez[z];
        o0[j] = f2bf(v * inv);
    }
    #pragma unroll
    for (int j = 0; j < 8; ++j) {
        float v = 0.f;
        #pragma unroll
        for (int z = 0; z < NSPLIT; ++z)
            v += pacc[b[z] + q * 64 + ds + 8 + j] * ez[z];
        o1[j] = f2bf(v * inv);
    }
    size_t ob = (size_t)(qt * 64 + q) * NFEAT + h * DK + ds;
    *reinterpret_cast<bf16x8*>(&ctxb[ob]) = o0;
    *reinterpret_cast<bf16x8*>(&ctxb[ob + 8]) = o1;
}

extern "C" void kernel_launch(void* const* d_in, const int* in_sizes, int n_in,
                              void* d_out, int out_size, void* d_ws, size_t ws_size,
                              hipStream_t stream) {
    const float* x   = (const float*)d_in[0];
    const float* Wq  = (const float*)d_in[1];
    const float* bq  = (const float*)d_in[2];
    const float* Wk  = (const float*)d_in[3];
    const float* bk  = (const float*)d_in[4];
    const float* Wv  = (const float*)d_in[5];
    const float* bv  = (const float*)d_in[6];
    const float* Wo  = (const float*)d_in[7];
    const float* bo  = (const float*)d_in[8];
    const float* kc  = (const float*)d_in[9];
    const float* vc  = (const float*)d_in[10];
    const int*   bt  = (const int*)d_in[11];
    const int*   so  = (const int*)d_in[12];

    short* xb   = (short*)d_ws;                       // 1M bf16
    short* Wt   = xb + (size_t)1024 * 1024;           // 4M bf16
    short* qkvb = Wt + (size_t)4096 * 1024;           // 3M bf16
    short* kg   = qkvb + (size_t)1024 * 3072;         // 4M bf16
    short* vtb  = kg + (size_t)NHEAD * MAXTOK * DK;   // 4M bf16
    float* pacc = (float*)(vtb + (size_t)NHEAD * DK * MAXTOK);  // NSPLIT*256*4224 f32
    short* ctxb = (short*)(pacc + (size_t)NSPLIT * 256 * 4224); // 1M bf16

    pack_kernel<<<dim3(1152), 256, 0, stream>>>(x, Wq, Wk, Wv, Wo, xb, Wt);
    qkv_gemm<<<dim3(24, 16), 256, 0, stream>>>(xb, Wt, bq, bk, bv, qkvb);
    gather_kv<<<dim3(16, 64), 256, 0, stream>>>(kc, vc, qkvb, bt, so, kg, vtb);
    attn_mfma<<<dim3(16, 16, NSPLIT), 256, 0, stream>>>(qkvb, kg, vtb, so, pacc);
    merge_ctx<<<dim3(16, 16), 256, 0, stream>>>(pacc, ctxb);
    out_gemm<<<dim3(16, 16), 256, 0, stream>>>(ctxb, Wt, bo, (float*)d_out);
}

// Round 9
// 104.803 us; speedup vs baseline: 2.1796x; 1.0737x over previous
//
#include <hip/hip_runtime.h>
#include <hip/hip_bf16.h>

#define NFEAT 1024
#define NHEAD 16
#define DK 64
#define TCHUNK 1024
#define MAXTOK 4096
#define NSPLIT 4

using bf16x8 = __attribute__((ext_vector_type(8))) short;
using f32x4  = __attribute__((ext_vector_type(4))) float;

__device__ __forceinline__ short f2bf(float f) {
    __hip_bfloat16 h = __float2bfloat16(f);
    return *reinterpret_cast<short*>(&h);
}

__device__ __forceinline__ float exp2fast(float x) {
    return __builtin_amdgcn_exp2f(x);
}

// log2(e)/sqrt(DK): folds the 1/sqrt(64) and the exp->exp2 conversion
#define QSCALE 0.1803368801f

// ---------------------------------------------------------------------------
// pack: blocks [0,1024): transpose+convert W{q,k,v,o} -> Wt[4096 n][1024 k]
//       blocks [1024,1152): convert x -> xb bf16
//       blocks [1152,1920): gather cache tokens -> kg[h][tok][d], vt[h][d][tok]
// ---------------------------------------------------------------------------
__global__ __launch_bounds__(256) void pack_kernel(
    const float* __restrict__ x,
    const float* __restrict__ Wq, const float* __restrict__ Wk,
    const float* __restrict__ Wv, const float* __restrict__ Wo,
    const float* __restrict__ kc, const float* __restrict__ vc,
    const int* __restrict__ btab, const int* __restrict__ soff,
    short* __restrict__ xb, short* __restrict__ Wt,
    short* __restrict__ kg, short* __restrict__ vt) {
    const int b = blockIdx.x;
    const int t = threadIdx.x;
    if (b < 1024) {
        __shared__ short T[64][72];
        const int w = b >> 8, tile = b & 255;
        const int k0 = (tile >> 4) << 6, n0 = (tile & 15) << 6;
        const float* W = (w == 0) ? Wq : (w == 1) ? Wk : (w == 2) ? Wv : Wo;
        const int r = t >> 2, cs = (t & 3) << 4;
        #pragma unroll
        for (int u = 0; u < 4; ++u) {
            float4 v = *reinterpret_cast<const float4*>(
                &W[(size_t)(k0 + r) * NFEAT + n0 + cs + u * 4]);
            T[cs + u * 4 + 0][r] = f2bf(v.x);
            T[cs + u * 4 + 1][r] = f2bf(v.y);
            T[cs + u * 4 + 2][r] = f2bf(v.z);
            T[cs + u * 4 + 3][r] = f2bf(v.w);
        }
        __syncthreads();
        const int c = t >> 2, rs = (t & 3) << 4;
        bf16x8 a0 = *reinterpret_cast<const bf16x8*>(&T[c][rs]);
        bf16x8 a1 = *reinterpret_cast<const bf16x8*>(&T[c][rs + 8]);
        size_t drow = (size_t)(w * 1024 + n0 + c) * NFEAT + k0 + rs;
        *reinterpret_cast<bf16x8*>(&Wt[drow]) = a0;
        *reinterpret_cast<bf16x8*>(&Wt[drow + 8]) = a1;
    } else if (b < 1152) {
        const int e0 = ((b - 1024) * 256 + t) * 32;
        #pragma unroll
        for (int u = 0; u < 4; ++u) {
            float4 v0 = *reinterpret_cast<const float4*>(&x[e0 + u * 8]);
            float4 v1 = *reinterpret_cast<const float4*>(&x[e0 + u * 8 + 4]);
            bf16x8 o;
            o[0] = f2bf(v0.x); o[1] = f2bf(v0.y); o[2] = f2bf(v0.z); o[3] = f2bf(v0.w);
            o[4] = f2bf(v1.x); o[5] = f2bf(v1.y); o[6] = f2bf(v1.z); o[7] = f2bf(v1.w);
            *reinterpret_cast<bf16x8*>(&xb[e0 + u * 8]) = o;
        }
    } else {
        // cache-token gather (tokens [0, offset))
        __shared__ short TV[64][72];
        const int cb = b - 1152;
        const int h = cb & 15;
        const int t0 = (cb >> 4) << 6;
        const int offset = soff[0];
        const int row = t >> 2, ds = (t & 3) << 4;
        const int tok = t0 + row;
        short kv[16], vv[16];
        if (tok < offset) {
            int phys = btab[tok >> 5];
            size_t base = ((size_t)(phys * 32 + (tok & 31)) * NHEAD + h) * DK + ds;
            #pragma unroll
            for (int u = 0; u < 4; ++u) {
                float4 kf = *reinterpret_cast<const float4*>(&kc[base + u * 4]);
                float4 vf = *reinterpret_cast<const float4*>(&vc[base + u * 4]);
                kv[u * 4 + 0] = f2bf(kf.x); kv[u * 4 + 1] = f2bf(kf.y);
                kv[u * 4 + 2] = f2bf(kf.z); kv[u * 4 + 3] = f2bf(kf.w);
                vv[u * 4 + 0] = f2bf(vf.x); vv[u * 4 + 1] = f2bf(vf.y);
                vv[u * 4 + 2] = f2bf(vf.z); vv[u * 4 + 3] = f2bf(vf.w);
            }
        } else {
            #pragma unroll
            for (int e = 0; e < 16; ++e) { kv[e] = 0; vv[e] = 0; }
        }
        {
            bf16x8 a, bb;
            #pragma unroll
            for (int e = 0; e < 8; ++e) { a[e] = kv[e]; bb[e] = kv[8 + e]; }
            size_t kb = ((size_t)h * MAXTOK + tok) * DK + ds;
            *reinterpret_cast<bf16x8*>(&kg[kb]) = a;
            *reinterpret_cast<bf16x8*>(&kg[kb + 8]) = bb;
        }
        #pragma unroll
        for (int e = 0; e < 16; ++e) TV[ds + e][row] = vv[e];
        __syncthreads();
        {
            const int d = t >> 2, ts = (t & 3) << 4;
            bf16x8 a = *reinterpret_cast<const bf16x8*>(&TV[d][ts]);
            bf16x8 bb = *reinterpret_cast<const bf16x8*>(&TV[d][ts + 8]);
            size_t vb = ((size_t)h * DK + d) * MAXTOK + t0 + ts;
            *reinterpret_cast<bf16x8*>(&vt[vb]) = a;
            *reinterpret_cast<bf16x8*>(&vt[vb + 8]) = bb;
        }
    }
}

// ---------------------------------------------------------------------------
// QKV MFMA GEMM. sel==0 -> qbuf (scaled); sel==1 -> kg new-token region;
// sel==2 -> vt new-token region (transposed scatter).
// ---------------------------------------------------------------------------
__global__ __launch_bounds__(256) void qkv_gemm(
    const short* __restrict__ xb, const short* __restrict__ Wt,
    const float* __restrict__ bq, const float* __restrict__ bk,
    const float* __restrict__ bv, const int* __restrict__ soff,
    short* __restrict__ qbuf, short* __restrict__ kg, short* __restrict__ vt) {
    __shared__ short As[64][72];
    __shared__ short Bs[128][72];
    const int tid = threadIdx.x;
    const int lane = tid & 63;
    const int w = tid >> 6;
    const int l15 = lane & 15, lg = lane >> 4;
    const int wr = w >> 1, wc = w & 1;
    const int m0 = blockIdx.y << 6, n0 = blockIdx.x << 7;
    const int sel = n0 >> 10;
    const float* bias = (sel == 0) ? bq : (sel == 1) ? bk : bv;

    f32x4 acc[2][4];
    #pragma unroll
    for (int i = 0; i < 2; ++i)
        #pragma unroll
        for (int j = 0; j < 4; ++j) acc[i][j] = (f32x4){0.f, 0.f, 0.f, 0.f};

    for (int k0 = 0; k0 < NFEAT; k0 += 64) {
        #pragma unroll
        for (int r = 0; r < 2; ++r) {
            int f = tid + (r << 8);
            int row = f >> 3, kc = (f & 7) << 3;
            *reinterpret_cast<bf16x8*>(&As[row][kc]) =
                *reinterpret_cast<const bf16x8*>(&xb[(size_t)(m0 + row) * NFEAT + k0 + kc]);
        }
        #pragma unroll
        for (int r = 0; r < 4; ++r) {
            int f = tid + (r << 8);
            int row = f >> 3, kc = (f & 7) << 3;
            *reinterpret_cast<bf16x8*>(&Bs[row][kc]) =
                *reinterpret_cast<const bf16x8*>(&Wt[(size_t)(n0 + row) * NFEAT + k0 + kc]);
        }
        __syncthreads();
        #pragma unroll
        for (int kk = 0; kk < 2; ++kk) {
            bf16x8 am[2], bn[4];
            #pragma unroll
            for (int mi = 0; mi < 2; ++mi)
                am[mi] = *reinterpret_cast<const bf16x8*>(
                    &As[wr * 32 + mi * 16 + l15][kk * 32 + lg * 8]);
            #pragma unroll
            for (int ni = 0; ni < 4; ++ni)
                bn[ni] = *reinterpret_cast<const bf16x8*>(
                    &Bs[wc * 64 + ni * 16 + l15][kk * 32 + lg * 8]);
            #pragma unroll
            for (int mi = 0; mi < 2; ++mi)
                #pragma unroll
                for (int ni = 0; ni < 4; ++ni)
                    acc[mi][ni] = __builtin_amdgcn_mfma_f32_16x16x32_bf16(
                        am[mi], bn[ni], acc[mi][ni], 0, 0, 0);
        }
        __syncthreads();
    }
    const int offs = soff[0];
    #pragma unroll
    for (int mi = 0; mi < 2; ++mi)
        #pragma unroll
        for (int rr = 0; rr < 4; ++rr) {
            int m = m0 + wr * 32 + mi * 16 + lg * 4 + rr;
            #pragma unroll
            for (int ni = 0; ni < 4; ++ni) {
                int n = n0 + wc * 64 + ni * 16 + l15;
                float v = acc[mi][ni][rr] + bias[n & 1023];
                if (sel == 0) {
                    qbuf[(size_t)m * NFEAT + n] = f2bf(v * QSCALE);
                } else if (sel == 1) {
                    int nn = n - 1024, hh = nn >> 6, dd = nn & 63;
                    kg[((size_t)hh * MAXTOK + offs + m) * DK + dd] = f2bf(v);
                } else {
                    int nn = n - 2048, hh = nn >> 6, dd = nn & 63;
                    vt[((size_t)hh * DK + dd) * MAXTOK + offs + m] = f2bf(v);
                }
            }
        }
}

// ---------------------------------------------------------------------------
// Output MFMA GEMM: out[1024][1024] f32 = ctxb @ Wo + bo.
// ---------------------------------------------------------------------------
__global__ __launch_bounds__(256) void out_gemm(
    const short* __restrict__ ctxb, const short* __restrict__ Wt,
    const float* __restrict__ bo, float* __restrict__ out) {
    __shared__ short As[64][72];
    __shared__ short Bs[64][72];
    const int tid = threadIdx.x;
    const int lane = tid & 63;
    const int w = tid >> 6;
    const int l15 = lane & 15, lg = lane >> 4;
    const int wr = w >> 1, wc = w & 1;
    const int m0 = blockIdx.y << 6, n0 = blockIdx.x << 6;

    f32x4 acc[2][2];
    #pragma unroll
    for (int i = 0; i < 2; ++i)
        #pragma unroll
        for (int j = 0; j < 2; ++j) acc[i][j] = (f32x4){0.f, 0.f, 0.f, 0.f};

    for (int k0 = 0; k0 < NFEAT; k0 += 64) {
        #pragma unroll
        for (int r = 0; r < 2; ++r) {
            int f = tid + (r << 8);
            int row = f >> 3, kc = (f & 7) << 3;
            *reinterpret_cast<bf16x8*>(&As[row][kc]) =
                *reinterpret_cast<const bf16x8*>(&ctxb[(size_t)(m0 + row) * NFEAT + k0 + kc]);
            *reinterpret_cast<bf16x8*>(&Bs[row][kc]) =
                *reinterpret_cast<const bf16x8*>(
                    &Wt[(size_t)(3072 + n0 + row) * NFEAT + k0 + kc]);
        }
        __syncthreads();
        #pragma unroll
        for (int kk = 0; kk < 2; ++kk) {
            bf16x8 am[2], bn[2];
            #pragma unroll
            for (int mi = 0; mi < 2; ++mi)
                am[mi] = *reinterpret_cast<const bf16x8*>(
                    &As[wr * 32 + mi * 16 + l15][kk * 32 + lg * 8]);
            #pragma unroll
            for (int ni = 0; ni < 2; ++ni)
                bn[ni] = *reinterpret_cast<const bf16x8*>(
                    &Bs[wc * 32 + ni * 16 + l15][kk * 32 + lg * 8]);
            #pragma unroll
            for (int mi = 0; mi < 2; ++mi)
                #pragma unroll
                for (int ni = 0; ni < 2; ++ni)
                    acc[mi][ni] = __builtin_amdgcn_mfma_f32_16x16x32_bf16(
                        am[mi], bn[ni], acc[mi][ni], 0, 0, 0);
        }
        __syncthreads();
    }
    #pragma unroll
    for (int mi = 0; mi < 2; ++mi)
        #pragma unroll
        for (int rr = 0; rr < 4; ++rr) {
            int m = m0 + wr * 32 + mi * 16 + lg * 4 + rr;
            #pragma unroll
            for (int ni = 0; ni < 2; ++ni) {
                int n = n0 + wc * 32 + ni * 16 + l15;
                out[(size_t)m * NFEAT + n] = acc[mi][ni][rr] + bo[n];
            }
        }
}

// ---------------------------------------------------------------------------
// MFMA flash attention v9. Grid (16 h, 16 qt, NSPLIT z), block 128 (2 waves).
// Each wave owns 32 q-rows (2 A-frag sets) -> K/V LDS fragments loaded once
// into registers and reused by both sets: LDS-read per q halved vs v5
// (the measured bottleneck). v5 sync structure (2 barriers/tile, register
// prefetch). Defer-max, ones-MFMA row-sum, exp2 domain.
// ---------------------------------------------------------------------------
__global__ __launch_bounds__(128, 2) void attn_mfma(
    const short* __restrict__ qbuf, const short* __restrict__ kg,
    const short* __restrict__ vt, const int* __restrict__ soff,
    float* __restrict__ pacc) {
    __shared__ short Ks[64][72];
    __shared__ short Vs[64][72];   // [d][tok]
    __shared__ short Ps[2][32][72];

    const int tid = threadIdx.x;
    const int lane = tid & 63;
    const int w = tid >> 6;        // 0/1
    const int l15 = lane & 15;
    const int lg = lane >> 4;
    const int h = blockIdx.x;
    const int qt = blockIdx.y;
    const int z = blockIdx.z;
    const int offset = soff[0];
    const int total = offset + TCHUNK;
    const int ntiles = (total + 63) >> 6;
    const int NT = (ntiles + NSPLIT - 1) / NSPLIT;
    const int tbase = z * NT;
    const int tend = min(tbase + NT, ntiles);

    const int srow = tid >> 1;           // 0..63 (tok for K, d for V)
    const int sseg = (tid & 1) << 5;     // 0 or 32

    const short* kbase = kg + (size_t)h * MAXTOK * DK;
    const short* vbase = vt + (size_t)h * DK * MAXTOK;

    // Q A-fragments: set s covers q = qt*64 + w*32 + s*16 + l15
    bf16x8 aq[2][2];
    #pragma unroll
    for (int set = 0; set < 2; ++set) {
        size_t qrow = (size_t)(qt * 64 + w * 32 + set * 16 + l15) * NFEAT + h * DK;
        aq[set][0] = *reinterpret_cast<const bf16x8*>(&qbuf[qrow + lg * 8]);
        aq[set][1] = *reinterpret_cast<const bf16x8*>(&qbuf[qrow + 32 + lg * 8]);
    }

    bf16x8 ones;
    #pragma unroll
    for (int e = 0; e < 8; ++e) ones[e] = (short)0x3F80;   // bf16 1.0

    float m[2][4];
    f32x4 acc[2][4], acc1[2];
    #pragma unroll
    for (int set = 0; set < 2; ++set) {
        #pragma unroll
        for (int r = 0; r < 4; ++r) m[set][r] = -1e30f;
        #pragma unroll
        for (int fc = 0; fc < 4; ++fc) acc[set][fc] = (f32x4){0.f, 0.f, 0.f, 0.f};
        acc1[set] = (f32x4){0.f, 0.f, 0.f, 0.f};
    }

    bf16x8 kr[4], vr[4];
    if (tbase < tend) {
        int tok0 = tbase << 6;
        #pragma unroll
        for (int j = 0; j < 4; ++j) {
            kr[j] = *reinterpret_cast<const bf16x8*>(
                &kbase[(size_t)(tok0 + srow) * DK + sseg + j * 8]);
            vr[j] = *reinterpret_cast<const bf16x8*>(
                &vbase[(size_t)srow * MAXTOK + tok0 + sseg + j * 8]);
        }
    }

    for (int t = tbase; t < tend; ++t) {
        __syncthreads();   // previous tile fully consumed
        #pragma unroll
        for (int j = 0; j < 4; ++j) {
            *reinterpret_cast<bf16x8*>(&Ks[srow][sseg + j * 8]) = kr[j];
            *reinterpret_cast<bf16x8*>(&Vs[srow][sseg + j * 8]) = vr[j];
        }
        __syncthreads();   // staged tile visible
        if (t + 1 < tend) {   // prefetch next tile into regs
            int tok0 = (t + 1) << 6;
            #pragma unroll
            for (int j = 0; j < 4; ++j) {
                kr[j] = *reinterpret_cast<const bf16x8*>(
                    &kbase[(size_t)(tok0 + srow) * DK + sseg + j * 8]);
                vr[j] = *reinterpret_cast<const bf16x8*>(
                    &vbase[(size_t)srow * MAXTOK + tok0 + sseg + j * 8]);
            }
        }

        const int kt0 = t << 6;
        // ---- K fragments: read ONCE, reused by both q-sets ----
        bf16x8 kb0[4], kb1[4];
        #pragma unroll
        for (int fc = 0; fc < 4; ++fc) {
            kb0[fc] = *reinterpret_cast<const bf16x8*>(&Ks[fc * 16 + l15][lg * 8]);
            kb1[fc] = *reinterpret_cast<const bf16x8*>(&Ks[fc * 16 + l15][32 + lg * 8]);
        }
        #pragma unroll
        for (int set = 0; set < 2; ++set) {
            // ---- QK^T ----
            f32x4 s[4];
            __builtin_amdgcn_s_setprio(1);
            #pragma unroll
            for (int fc = 0; fc < 4; ++fc) {
                s[fc] = __builtin_amdgcn_mfma_f32_16x16x32_bf16(
                    aq[set][0], kb0[fc], (f32x4){0.f, 0.f, 0.f, 0.f}, 0, 0, 0);
                s[fc] = __builtin_amdgcn_mfma_f32_16x16x32_bf16(
                    aq[set][1], kb1[fc], s[fc], 0, 0, 0);
            }
            __builtin_amdgcn_s_setprio(0);
            if (kt0 + 64 > total) {
                #pragma unroll
                for (int fc = 0; fc < 4; ++fc) {
                    bool valid = (kt0 + fc * 16 + l15) < total;
                    #pragma unroll
                    for (int r = 0; r < 4; ++r)
                        s[fc][r] = valid ? s[fc][r] : -1e30f;
                }
            }
            // ---- defer-max online softmax ----
            float lm[4];
            #pragma unroll
            for (int r = 0; r < 4; ++r)
                lm[r] = fmaxf(fmaxf(s[0][r], s[1][r]), fmaxf(s[2][r], s[3][r]));
            bool ok = lm[0] <= m[set][0] + 8.f && lm[1] <= m[set][1] + 8.f &&
                      lm[2] <= m[set][2] + 8.f && lm[3] <= m[set][3] + 8.f;
            if (!__all(ok)) {
                #pragma unroll
                for (int r = 0; r < 4; ++r) {
                    float tm = lm[r];
                    tm = fmaxf(tm, __shfl_xor(tm, 1));
                    tm = fmaxf(tm, __shfl_xor(tm, 2));
                    tm = fmaxf(tm, __shfl_xor(tm, 4));
                    tm = fmaxf(tm, __shfl_xor(tm, 8));
                    float mn = fmaxf(m[set][r], tm);
                    float sc = exp2fast(m[set][r] - mn);
                    m[set][r] = mn;
                    acc1[set][r] *= sc;
                    #pragma unroll
                    for (int fc = 0; fc < 4; ++fc) acc[set][fc][r] *= sc;
                }
            }
            // ---- P -> per-wave LDS (D layout -> A-frag layout) ----
            #pragma unroll
            for (int fc = 0; fc < 4; ++fc)
                #pragma unroll
                for (int r = 0; r < 4; ++r)
                    Ps[w][set * 16 + lg * 4 + r][l15 + 16 * fc] =
                        f2bf(exp2fast(s[fc][r] - m[set][r]));
        }
        // ---- PV: V fragments read once, used by both sets ----
        #pragma unroll
        for (int ks = 0; ks < 2; ++ks) {
            bf16x8 pa0 = *reinterpret_cast<const bf16x8*>(
                &Ps[w][l15][ks * 32 + lg * 8]);
            bf16x8 pa1 = *reinterpret_cast<const bf16x8*>(
                &Ps[w][16 + l15][ks * 32 + lg * 8]);
            __builtin_amdgcn_s_setprio(1);
            acc1[0] = __builtin_amdgcn_mfma_f32_16x16x32_bf16(pa0, ones, acc1[0], 0, 0, 0);
            acc1[1] = __builtin_amdgcn_mfma_f32_16x16x32_bf16(pa1, ones, acc1[1], 0, 0, 0);
            #pragma unroll
            for (int fc = 0; fc < 4; ++fc) {
                bf16x8 bv = *reinterpret_cast<const bf16x8*>(
                    &Vs[fc * 16 + l15][ks * 32 + lg * 8]);
                acc[0][fc] = __builtin_amdgcn_mfma_f32_16x16x32_bf16(pa0, bv, acc[0][fc], 0, 0, 0);
                acc[1][fc] = __builtin_amdgcn_mfma_f32_16x16x32_bf16(pa1, bv, acc[1][fc], 0, 0, 0);
            }
            __builtin_amdgcn_s_setprio(0);
        }
    }

    // ---- write this split's partial (unnormalized) ----
    const size_t pbase = (((size_t)z * NHEAD + h) * 16 + qt) * 4224;
    #pragma unroll
    for (int set = 0; set < 2; ++set)
        #pragma unroll
        for (int r = 0; r < 4; ++r) {
            int q = w * 32 + set * 16 + lg * 4 + r;
            if (l15 == 0) {
                pacc[pbase + 4096 + q] = m[set][r];
                pacc[pbase + 4160 + q] = acc1[set][r];
            }
            #pragma unroll
            for (int fc = 0; fc < 4; ++fc)
                pacc[pbase + q * 64 + l15 + 16 * fc] = acc[set][fc][r];
        }
}

// ---------------------------------------------------------------------------
// merge NSPLIT split partials -> ctxb bf16 [1024 t][1024 (h*64+d)]
// ---------------------------------------------------------------------------
__global__ __launch_bounds__(256) void merge_ctx(
    const float* __restrict__ pacc, short* __restrict__ ctxb) {
    const int h = blockIdx.x, qt = blockIdx.y;
    const int t = threadIdx.x;
    const int q = t >> 2, ds = (t & 3) << 4;
    size_t b[NSPLIT];
    float mz[NSPLIT], lz[NSPLIT];
    float M = -1e30f;
    #pragma unroll
    for (int z = 0; z < NSPLIT; ++z) {
        b[z] = (((size_t)z * NHEAD + h) * 16 + qt) * 4224;
        mz[z] = pacc[b[z] + 4096 + q];
        lz[z] = pacc[b[z] + 4160 + q];
        M = fmaxf(M, mz[z]);
    }
    float L = 0.f, ez[NSPLIT];
    #pragma unroll
    for (int z = 0; z < NSPLIT; ++z) {
        ez[z] = __builtin_amdgcn_exp2f(mz[z] - M);
        L += lz[z] * ez[z];
    }
    float inv = 1.f / L;
    bf16x8 o0, o1;
    #pragma unroll
    for (int j = 0; j < 8; ++j) {
        float v = 0.f;
        #pragma unroll
        for (int z = 0; z < NSPLIT; ++z)
            v += pacc[b[z] + q * 64 + ds + j] * ez[z];
        o0[j] = f2bf(v * inv);
    }
    #pragma unroll
    for (int j = 0; j < 8; ++j) {
        float v = 0.f;
        #pragma unroll
        for (int z = 0; z < NSPLIT; ++z)
            v += pacc[b[z] + q * 64 + ds + 8 + j] * ez[z];
        o1[j] = f2bf(v * inv);
    }
    size_t ob = (size_t)(qt * 64 + q) * NFEAT + h * DK + ds;
    *reinterpret_cast<bf16x8*>(&ctxb[ob]) = o0;
    *reinterpret_cast<bf16x8*>(&ctxb[ob + 8]) = o1;
}

extern "C" void kernel_launch(void* const* d_in, const int* in_sizes, int n_in,
                              void* d_out, int out_size, void* d_ws, size_t ws_size,
                              hipStream_t stream) {
    const float* x   = (const float*)d_in[0];
    const float* Wq  = (const float*)d_in[1];
    const float* bq  = (const float*)d_in[2];
    const float* Wk  = (const float*)d_in[3];
    const float* bk  = (const float*)d_in[4];
    const float* Wv  = (const float*)d_in[5];
    const float* bv  = (const float*)d_in[6];
    const float* Wo  = (const float*)d_in[7];
    const float* bo  = (const float*)d_in[8];
    const float* kc  = (const float*)d_in[9];
    const float* vc  = (const float*)d_in[10];
    const int*   bt  = (const int*)d_in[11];
    const int*   so  = (const int*)d_in[12];

    short* xb   = (short*)d_ws;                       // 1M bf16
    short* Wt   = xb + (size_t)1024 * 1024;           // 4M bf16
    short* qbuf = Wt + (size_t)4096 * 1024;           // 1M bf16
    short* kg   = qbuf + (size_t)1024 * 1024;         // 4M bf16
    short* vtb  = kg + (size_t)NHEAD * MAXTOK * DK;   // 4M bf16
    float* pacc = (float*)(vtb + (size_t)NHEAD * DK * MAXTOK);  // NSPLIT*256*4224 f32
    short* ctxb = (short*)(pacc + (size_t)NSPLIT * 256 * 4224); // 1M bf16

    pack_kernel<<<dim3(1920), 256, 0, stream>>>(x, Wq, Wk, Wv, Wo, kc, vc, bt, so,
                                                xb, Wt, kg, vtb);
    qkv_gemm<<<dim3(24, 16), 256, 0, stream>>>(xb, Wt, bq, bk, bv, so,
                                               qbuf, kg, vtb);
    attn_mfma<<<dim3(16, 16, NSPLIT), 128, 0, stream>>>(qbuf, kg, vtb, so, pacc);
    merge_ctx<<<dim3(16, 16), 256, 0, stream>>>(pacc, ctxb);
    out_gemm<<<dim3(16, 16), 256, 0, stream>>>(ctxb, Wt, bo, (float*)d_out);
}